// Round 8
// baseline (182.072 us; speedup 1.0000x reference)
//
#include <hip/hip_runtime.h>
#include <math.h>

// VectorQuantizer on MI355X — R8: register-resident W, phase-free main loop.
// R5-R7 falsified traffic/TLP/request-shape; the invariant cost is the block
// phase skeleton (stage->barrier->scan->barrier->epilogue). R8 deletes it:
// each wave holds B-frags for 256 codes in ~128 VGPRs (loaded once from
// L2-hot w) + 16 seed regs, then streams 128 tokens in 8 barrier-free passes
// (gather 16 lines/instr fully used, MFMA from registers, u32-key argmin).
// Wave pairs (code-halves) combine keys via one LDS buffer + ONE barrier.
// Numerics: same f2bf/-2x/seeded-acc/u32-key scheme as R4-R7; wsq now
// shfl-summed (order drift ~1e-7, harmless). Fence-free fused tail as R7.
// ws: [0,2048) counts f32[512] | [2048,2056) sse f64 | [2056,2060) ticket u32

#define NTOK 131072
#define KCODES 512
#define HW 4096
#define CHW 262144
#define NELEM 8388608

typedef __attribute__((ext_vector_type(8))) short short8;
typedef __attribute__((ext_vector_type(4))) float f32x4;

static __device__ __forceinline__ unsigned short f2bf(float f) {
    unsigned u = __float_as_uint(f);
    unsigned r = u + 0x7FFFu + ((u >> 16) & 1u);  // RNE
    return (unsigned short)(r >> 16);
}

__global__ __launch_bounds__(256, 2) void vq_main(const float* __restrict__ in,
                                                  const float* __restrict__ w,
                                                  float* __restrict__ out,
                                                  float* __restrict__ counts,
                                                  double* __restrict__ sse_acc,
                                                  unsigned* __restrict__ ticket) {
    __shared__ unsigned kbuf[2][256];  // per-half argmin keys for 256 tokens
    __shared__ double red[512];        // tail reduction (also after-combine idx)
    __shared__ unsigned lastflag;

    const int tid = threadIdx.x;
    const int lane = tid & 63, wv = tid >> 6;       // 4 waves
    const int col = lane & 15, quad = lane >> 4;
    const int pair = wv >> 1, half = wv & 1;        // pair: token group; half: codes
    const int base = blockIdx.x * 256;              // block's 256 tokens
    const int pbase = base + pair * 128;            // this pair's 128 tokens

    // ---- load this wave's 256-code B-frags into registers (L2-hot w) ----
    short8 b[16][2];
    float wsqr[16];
#pragma unroll
    for (int tt = 0; tt < 16; ++tt) {
        const int row = half * 256 + tt * 16 + col;
        const float4* wr = (const float4*)(w + row * 64 + quad * 8);
        const float4 f0 = wr[0], f1 = wr[1];        // dims quad*8 .. +8
        const float4 f2 = wr[8], f3 = wr[9];        // dims 32+quad*8 .. +8
        short8 b0, b1;
        b0[0] = (short)f2bf(f0.x); b0[1] = (short)f2bf(f0.y);
        b0[2] = (short)f2bf(f0.z); b0[3] = (short)f2bf(f0.w);
        b0[4] = (short)f2bf(f1.x); b0[5] = (short)f2bf(f1.y);
        b0[6] = (short)f2bf(f1.z); b0[7] = (short)f2bf(f1.w);
        b1[0] = (short)f2bf(f2.x); b1[1] = (short)f2bf(f2.y);
        b1[2] = (short)f2bf(f2.z); b1[3] = (short)f2bf(f2.w);
        b1[4] = (short)f2bf(f3.x); b1[5] = (short)f2bf(f3.y);
        b1[6] = (short)f2bf(f3.z); b1[7] = (short)f2bf(f3.w);
        b[tt][0] = b0; b[tt][1] = b1;
        float ws2 = f0.x * f0.x;
        ws2 = fmaf(f0.y, f0.y, ws2); ws2 = fmaf(f0.z, f0.z, ws2);
        ws2 = fmaf(f0.w, f0.w, ws2); ws2 = fmaf(f1.x, f1.x, ws2);
        ws2 = fmaf(f1.y, f1.y, ws2); ws2 = fmaf(f1.z, f1.z, ws2);
        ws2 = fmaf(f1.w, f1.w, ws2); ws2 = fmaf(f2.x, f2.x, ws2);
        ws2 = fmaf(f2.y, f2.y, ws2); ws2 = fmaf(f2.z, f2.z, ws2);
        ws2 = fmaf(f2.w, f2.w, ws2); ws2 = fmaf(f3.x, f3.x, ws2);
        ws2 = fmaf(f3.y, f3.y, ws2); ws2 = fmaf(f3.z, f3.z, ws2);
        ws2 = fmaf(f3.w, f3.w, ws2);
        float t1 = ws2 + __shfl_xor(ws2, 16, 64);   // sum over quad bit 0
        wsqr[tt] = 1.25f + (t1 + __shfl_xor(t1, 32, 64));
    }

    // ---- stream 128 tokens in 8 barrier-free passes of 16 ----
    float xsq = 0.f;
#pragma unroll 1
    for (int p = 0; p < 8; ++p) {
        const int tok = pbase + p * 16 + col;       // A row m = col
        const float* xb = in + (tok >> 12) * CHW + (tok & 4095);
        short8 a0, a1;
#pragma unroll
        for (int j = 0; j < 8; ++j) {
            const float x0 = xb[(quad * 8 + j) * HW];
            const float x1 = xb[(32 + quad * 8 + j) * HW];
            xsq = fmaf(x0, x0, xsq);
            xsq = fmaf(x1, x1, xsq);
            a0[j] = (short)f2bf(-2.0f * x0);
            a1[j] = (short)f2bf(-2.0f * x1);
        }
        unsigned key[4] = {0xFFFFFFFFu, 0xFFFFFFFFu, 0xFFFFFFFFu, 0xFFFFFFFFu};
#pragma unroll
        for (int tt = 0; tt < 16; ++tt) {
            const float seed = wsqr[tt];
            f32x4 acc = {seed, seed, seed, seed};
            acc = __builtin_amdgcn_mfma_f32_16x16x32_bf16(a0, b[tt][0], acc, 0, 0, 0);
            acc = __builtin_amdgcn_mfma_f32_16x16x32_bf16(a1, b[tt][1], acc, 0, 0, 0);
            const unsigned code = (unsigned)(half * 256 + tt * 16 + col);
#pragma unroll
            for (int r = 0; r < 4; ++r) {
                const unsigned k = (__float_as_uint(acc[r]) << 9) | code;
                key[r] = k < key[r] ? k : key[r];
            }
        }
        // min across the 16 code-cols (lane bits 0..3)
#pragma unroll
        for (int s = 1; s < 16; s <<= 1)
#pragma unroll
            for (int r = 0; r < 4; ++r) {
                const unsigned o = __shfl_xor(key[r], s, 64);
                key[r] = o < key[r] ? o : key[r];
            }
        if (col == 0) {
#pragma unroll
            for (int r = 0; r < 4; ++r)
                kbuf[half][pair * 128 + p * 16 + quad * 4 + r] = key[r];
        }
    }
    __syncthreads();  // B1: all keys published

    // ---- combine halves; counts, SSE, idx publish (thread = token) ----
    const unsigned kA = kbuf[0][tid], kB = kbuf[1][tid];
    const unsigned k = kA < kB ? kA : kB;
    const int idx = (int)(k & 511u);
    atomicAdd(&counts[idx], 1.0f);
    float contrib = __uint_as_float((k >> 9) | 0x3F800000u) - 1.25f;
    if (half == 0) contrib += xsq;  // gather duplicated per half: count once
#pragma unroll
    for (int off = 32; off > 0; off >>= 1) contrib += __shfl_down(contrib, off, 64);
    if (lane == 0) atomicAdd(sse_acc, (double)contrib);
    ((int*)red)[tid] = idx;  // idx table for epilogue (red unused until tail)
    __syncthreads();  // B2: idx table visible

    // ---- epilogue: write w rows (L2-hot); 4 lanes/token, 4 passes ----
    const int* ibuf = (const int*)red;
#pragma unroll
    for (int p2 = 0; p2 < 4; ++p2) {
        const int tl = p2 * 64 + (tid >> 2), q = tid & 3;
        const float4* wr = (const float4*)(w + ibuf[tl] * 64 + q * 16);
        float4* op = (float4*)(out + (base + tl) * 64 + q * 16);
#pragma unroll
        for (int i = 0; i < 4; ++i) op[i] = wr[i];
    }

    // ---- fence-free fused tail (atomics-only cross-block state) ----
    __builtin_amdgcn_s_waitcnt(0);
    if (tid == 0) lastflag = (atomicAdd(ticket, 1u) == 511u) ? 1u : 0u;
    __syncthreads();
    if (lastflag) {
        __syncthreads();  // make sure epilogue ibuf reads are done before reuse
        const float c0 = atomicAdd(&counts[tid], 0.0f);
        const float c1 = atomicAdd(&counts[tid + 256], 0.0f);
        const double p0 = (double)c0 / (double)NTOK;
        const double p1 = (double)c1 / (double)NTOK;
        red[tid] = p0 * log(p0 + 1e-10);
        red[tid + 256] = p1 * log(p1 + 1e-10);
        __syncthreads();
#pragma unroll
        for (int s = 256; s > 0; s >>= 1) {
            if (tid < s) red[tid] += red[tid + s];
            __syncthreads();
        }
        if (tid == 0) {
            const double sv = atomicAdd(sse_acc, 0.0);
            out[NELEM] = (float)((sv / (double)NELEM) * 1.25);
            out[NELEM + 1] = (float)exp(-red[0]);
        }
    }
}

extern "C" void kernel_launch(void* const* d_in, const int* in_sizes, int n_in,
                              void* d_out, int out_size, void* d_ws, size_t ws_size,
                              hipStream_t stream) {
    const float* in = (const float*)d_in[0];
    const float* w = (const float*)d_in[1];
    float* out = (float*)d_out;

    char* ws = (char*)d_ws;
    float* counts = (float*)(ws + 0);
    double* sse_acc = (double*)(ws + 2048);
    unsigned* ticket = (unsigned*)(ws + 2056);

    hipMemsetAsync(ws, 0, 2060, stream);  // counts + sse + ticket
    vq_main<<<512, 256, 0, stream>>>(in, w, out, counts, sse_acc, ticket);
}

// Round 9
// 131.135 us; speedup vs baseline: 1.3884x; 1.3884x over previous
//
#include <hip/hip_runtime.h>
#include <math.h>

// VectorQuantizer on MI355X — R9: R6 minus ALL global atomics (single-variable).
// Falsified so far: traffic volume (R5), TLP (R6), request shape (R7),
// reg-resident W (R8: VGPR cap 128 -> spill, WRITE 36->71MB). Remaining
// invariant across the 80µs plateau: 131k device-scope atomicAdds to 512
// counts addresses (~256 collisions each, cross-XCD line ping-pong) + fp64
// atomics to ONE sse address — serialization at L2 slices that no SQ/TCC
// busy counter shows. R9: counts -> per-block LDS histogram stored as plain
// coalesced floats to partials[blk][512]; sse -> ssep[blk]; new vq_final
// reduces 1MB partials + 512 doubles. No memset, no ticket, no atomics.
// Host falls back to R6 atomic scheme if ws_size < 1.05MB (call-invariant).
// Numerics: R6-identical argmin path; sse order drift ~1e-13.
// ws (preferred): [0,1MB) partials f32[512][512] | [1MB,1MB+4K) ssep f64[512]

#define NTOK 131072
#define KCODES 512
#define HW 4096
#define CHW 262144
#define NELEM 8388608

typedef __attribute__((ext_vector_type(8))) short short8;
typedef __attribute__((ext_vector_type(4))) float f32x4;

static __device__ __forceinline__ unsigned short f2bf(float f) {
    unsigned u = __float_as_uint(f);
    unsigned r = u + 0x7FFFu + ((u >> 16) & 1u);  // RNE
    return (unsigned short)(r >> 16);
}

__global__ __launch_bounds__(512, 4) void vq_main(const float* __restrict__ in,
                                                  const float* __restrict__ w,
                                                  float* __restrict__ out,
                                                  float* __restrict__ pcounts,
                                                  double* __restrict__ ssep,
                                                  float* __restrict__ counts,
                                                  double* __restrict__ sse_acc,
                                                  const int amode) {
    __shared__ unsigned short wh[KCODES * 64];  // 65536 B, frag-packed bf16 W
    __shared__ float wsqp[KCODES];              // 2048 B: 1.25 + ||w_k||^2
    __shared__ int idxbuf[256];                 // 1024 B
    __shared__ int hist[KCODES];                // 2048 B block histogram
    __shared__ double sred[8];                  // per-wave sse partials

    const int tid = threadIdx.x;
    const int lane = tid & 63, wv = tid >> 6;   // wv in [0,8)
    const int col = lane & 15, quad = lane >> 4;
    const int ntok0 = blockIdx.x * 256;

    wsqp[tid] = 1.25f;
    hist[tid] = 0;
    __syncthreads();  // B1: wsqp/hist init before use

    // ---- interleaved: 1 W-staging chunk + 4 X gather dwords per iter (8) ----
    const float* gbase = in + (ntok0 >> 12) * CHW + (ntok0 & 4095) + wv * 32 + col;
    short8 ah[2][2];
    float xsq = 0.f;
#pragma unroll
    for (int it = 0; it < 8; ++it) {
        const int g = it * 512 + tid;
        const int cc = g & 15, qd = (g >> 4) & 3, ch = (g >> 6) & 1, tt = g >> 7;
        const float4* src = (const float4*)(w + (tt * 16 + cc) * 64 + ch * 32 + qd * 8);
        const float4 v0 = src[0], v1 = src[1];
        const int sub = it >> 2, c = (it >> 1) & 1, j0 = (it & 1) * 4;
        const float* gp = gbase + sub * 16 + (c * 32 + quad * 8 + j0) * HW;
        const float x0 = gp[0 * HW], x1 = gp[1 * HW], x2 = gp[2 * HW], x3 = gp[3 * HW];

        short8 hv;
        hv[0] = (short)f2bf(v0.x); hv[1] = (short)f2bf(v0.y);
        hv[2] = (short)f2bf(v0.z); hv[3] = (short)f2bf(v0.w);
        hv[4] = (short)f2bf(v1.x); hv[5] = (short)f2bf(v1.y);
        hv[6] = (short)f2bf(v1.z); hv[7] = (short)f2bf(v1.w);
        *(short8*)(wh + g * 8) = hv;
        float ws2 = v0.x * v0.x;
        ws2 = fmaf(v0.y, v0.y, ws2); ws2 = fmaf(v0.z, v0.z, ws2);
        ws2 = fmaf(v0.w, v0.w, ws2); ws2 = fmaf(v1.x, v1.x, ws2);
        ws2 = fmaf(v1.y, v1.y, ws2); ws2 = fmaf(v1.z, v1.z, ws2);
        ws2 = fmaf(v1.w, v1.w, ws2);
        atomicAdd(&wsqp[tt * 16 + cc], ws2);  // LDS atomic (exonerated by R4)

        ah[sub][c][j0 + 0] = (short)f2bf(-2.0f * x0);
        ah[sub][c][j0 + 1] = (short)f2bf(-2.0f * x1);
        ah[sub][c][j0 + 2] = (short)f2bf(-2.0f * x2);
        ah[sub][c][j0 + 3] = (short)f2bf(-2.0f * x3);
        xsq = fmaf(x0, x0, xsq); xsq = fmaf(x1, x1, xsq);
        xsq = fmaf(x2, x2, xsq); xsq = fmaf(x3, x3, xsq);
    }
    __syncthreads();  // B2: wh + wsqp complete

    // ---- scan 32 tiles of 16 codes; key = (float_bits(d)<<9)|code ----
    unsigned runkey[2][4];
#pragma unroll
    for (int sub = 0; sub < 2; ++sub)
#pragma unroll
        for (int r = 0; r < 4; ++r) runkey[sub][r] = 0xFFFFFFFFu;

#pragma unroll 1
    for (int t = 0; t < 32; ++t) {
        const unsigned short* ph = wh + t * 1024 + quad * 128 + col * 8;
        const short8 b0 = *(const short8*)ph;
        const short8 b1 = *(const short8*)(ph + 512);
        const int code = t * 16 + col;
        const float seed = wsqp[code];
#pragma unroll
        for (int sub = 0; sub < 2; ++sub) {
            f32x4 acc = {seed, seed, seed, seed};
            acc = __builtin_amdgcn_mfma_f32_16x16x32_bf16(ah[sub][0], b0, acc, 0, 0, 0);
            acc = __builtin_amdgcn_mfma_f32_16x16x32_bf16(ah[sub][1], b1, acc, 0, 0, 0);
#pragma unroll
            for (int r = 0; r < 4; ++r) {
                const unsigned key = (__float_as_uint(acc[r]) << 9) | code;
                runkey[sub][r] = key < runkey[sub][r] ? key : runkey[sub][r];
            }
        }
    }

    // ---- cross-lane argmin over the 16 code-cols ----
#pragma unroll
    for (int s = 1; s < 16; s <<= 1)
#pragma unroll
        for (int sub = 0; sub < 2; ++sub)
#pragma unroll
            for (int r = 0; r < 4; ++r) {
                const unsigned o = __shfl_xor(runkey[sub][r], s, 64);
                runkey[sub][r] = o < runkey[sub][r] ? o : runkey[sub][r];
            }

    // d_best (exact from key) + publish indices
    float dsum = 0.f;
    if (col == 0) {
#pragma unroll
        for (int sub = 0; sub < 2; ++sub)
#pragma unroll
            for (int r = 0; r < 4; ++r) {
                const unsigned key = runkey[sub][r];
                idxbuf[wv * 32 + sub * 16 + quad * 4 + r] = (int)(key & 511u);
                dsum += __uint_as_float((key >> 9) | 0x3F800000u) - 1.25f;
            }
    }
    float contrib = xsq + dsum;
#pragma unroll
    for (int off = 32; off > 0; off >>= 1) contrib += __shfl_down(contrib, off, 64);
    if (lane == 0) sred[wv] = (double)contrib;
    __syncthreads();  // B3: idxbuf + sred visible

    if (tid < 256) atomicAdd(&hist[idxbuf[tid]], 1);  // LDS histogram

    // ---- epilogue: write w rows only (L2-hot); 4 lanes/token, 2 passes ----
#pragma unroll
    for (int p = 0; p < 2; ++p) {
        const int tl = p * 16 + (lane >> 2), q = lane & 3;
        const int n = ntok0 + wv * 32 + tl;
        const int bidx = idxbuf[wv * 32 + tl];
        const float4* wr = (const float4*)(w + bidx * 64 + q * 16);
        float4* op = (float4*)(out + n * 64 + q * 16);
#pragma unroll
        for (int i = 0; i < 4; ++i) op[i] = wr[i];
    }
    __syncthreads();  // B4: hist complete

    if (!amode) {
        pcounts[(blockIdx.x << 9) + tid] = (float)hist[tid];  // plain store
        if (tid == 0) {
            double s = sred[0];
#pragma unroll
            for (int i = 1; i < 8; ++i) s += sred[i];
            ssep[blockIdx.x] = s;
        }
    } else {  // fallback: ws too small for partials
        const int h = hist[tid];
        if (h) atomicAdd(&counts[tid], (float)h);
        if (tid == 0) {
            double s = sred[0];
#pragma unroll
            for (int i = 1; i < 8; ++i) s += sred[i];
            atomicAdd(sse_acc, s);
        }
    }
}

// reduce partials: counts over 512 blocks + sse over 512 doubles
__global__ __launch_bounds__(512) void vq_final_p(const float* __restrict__ pcounts,
                                                  const double* __restrict__ ssep,
                                                  float* __restrict__ out) {
    __shared__ double red[512];
    __shared__ double sred[512];
    const int k = threadIdx.x;
    float s = 0.f;
#pragma unroll 8
    for (int b = 0; b < 512; ++b) s += pcounts[(b << 9) + k];  // coalesced
    const double p = (double)s / (double)NTOK;
    red[k] = p * log(p + 1e-10);
    sred[k] = ssep[k];
    __syncthreads();
#pragma unroll
    for (int st = 256; st > 0; st >>= 1) {
        if (k < st) { red[k] += red[k + st]; sred[k] += sred[k + st]; }
        __syncthreads();
    }
    if (k == 0) {
        out[NELEM] = (float)((sred[0] / (double)NELEM) * 1.25);
        out[NELEM + 1] = (float)exp(-red[0]);
    }
}

__global__ __launch_bounds__(512) void vq_final_a(const float* __restrict__ counts,
                                                  const double* __restrict__ sse_acc,
                                                  float* __restrict__ out) {
    __shared__ double red[512];
    const int k = threadIdx.x;
    const double p = (double)counts[k] / (double)NTOK;
    red[k] = p * log(p + 1e-10);
    __syncthreads();
#pragma unroll
    for (int st = 256; st > 0; st >>= 1) {
        if (k < st) red[k] += red[k + st];
        __syncthreads();
    }
    if (k == 0) {
        out[NELEM] = (float)((*sse_acc / (double)NELEM) * 1.25);
        out[NELEM + 1] = (float)exp(-red[0]);
    }
}

extern "C" void kernel_launch(void* const* d_in, const int* in_sizes, int n_in,
                              void* d_out, int out_size, void* d_ws, size_t ws_size,
                              hipStream_t stream) {
    const float* in = (const float*)d_in[0];
    const float* w = (const float*)d_in[1];
    float* out = (float*)d_out;
    char* ws = (char*)d_ws;

    const size_t need = (size_t)512 * 512 * 4 + 512 * 8;  // 1 MB + 4 KB
    if (ws_size >= need) {
        float* pcounts = (float*)ws;
        double* ssep = (double*)(ws + (size_t)512 * 512 * 4);
        vq_main<<<512, 512, 0, stream>>>(in, w, out, pcounts, ssep,
                                         nullptr, nullptr, 0);
        vq_final_p<<<1, 512, 0, stream>>>(pcounts, ssep, out);
    } else {  // fallback: R6-style atomics
        float* counts = (float*)ws;
        double* sse_acc = (double*)(ws + 2048);
        hipMemsetAsync(ws, 0, 2056, stream);
        vq_main<<<512, 512, 0, stream>>>(in, w, out, nullptr, nullptr,
                                         counts, sse_acc, 1);
        vq_final_a<<<1, 512, 0, stream>>>(counts, sse_acc, out);
    }
}

// Round 10
// 116.695 us; speedup vs baseline: 1.5602x; 1.1237x over previous
//
#include <hip/hip_runtime.h>
#include <math.h>

// VectorQuantizer on MI355X — R10: R9 main (bit-identical) + parallel reduction.
// R9 confirmed the atomic theory: removing 131k contended global atomicAdds +
// single-address fp64 atomics cut main 79.5 -> <43.6 µs (dropped out of top-5).
// Remaining controllable cost: vq_final_p was one block doing 512 column-sum
// batches (unroll 8 -> 64 dependent ~700cyc latency rounds on post-writeback
// data). R10: thread t owns 4 codes x 1 block-quarter -> float4 loads (1 KB
// per wave-instr, coalesced), 128 iters unroll-16 -> ~8 latency rounds, then
// 4x512 LDS combine + tree. Everything else untouched.
// ws (preferred): [0,1MB) partials f32[512][512] | [1MB,+4K) ssep f64[512]

#define NTOK 131072
#define KCODES 512
#define HW 4096
#define CHW 262144
#define NELEM 8388608

typedef __attribute__((ext_vector_type(8))) short short8;
typedef __attribute__((ext_vector_type(4))) float f32x4;

static __device__ __forceinline__ unsigned short f2bf(float f) {
    unsigned u = __float_as_uint(f);
    unsigned r = u + 0x7FFFu + ((u >> 16) & 1u);  // RNE
    return (unsigned short)(r >> 16);
}

__global__ __launch_bounds__(512, 4) void vq_main(const float* __restrict__ in,
                                                  const float* __restrict__ w,
                                                  float* __restrict__ out,
                                                  float* __restrict__ pcounts,
                                                  double* __restrict__ ssep,
                                                  float* __restrict__ counts,
                                                  double* __restrict__ sse_acc,
                                                  const int amode) {
    __shared__ unsigned short wh[KCODES * 64];  // 65536 B, frag-packed bf16 W
    __shared__ float wsqp[KCODES];              // 2048 B: 1.25 + ||w_k||^2
    __shared__ int idxbuf[256];                 // 1024 B
    __shared__ int hist[KCODES];                // 2048 B block histogram
    __shared__ double sred[8];                  // per-wave sse partials

    const int tid = threadIdx.x;
    const int lane = tid & 63, wv = tid >> 6;   // wv in [0,8)
    const int col = lane & 15, quad = lane >> 4;
    const int ntok0 = blockIdx.x * 256;

    wsqp[tid] = 1.25f;
    hist[tid] = 0;
    __syncthreads();  // B1: wsqp/hist init before use

    // ---- interleaved: 1 W-staging chunk + 4 X gather dwords per iter (8) ----
    const float* gbase = in + (ntok0 >> 12) * CHW + (ntok0 & 4095) + wv * 32 + col;
    short8 ah[2][2];
    float xsq = 0.f;
#pragma unroll
    for (int it = 0; it < 8; ++it) {
        const int g = it * 512 + tid;
        const int cc = g & 15, qd = (g >> 4) & 3, ch = (g >> 6) & 1, tt = g >> 7;
        const float4* src = (const float4*)(w + (tt * 16 + cc) * 64 + ch * 32 + qd * 8);
        const float4 v0 = src[0], v1 = src[1];
        const int sub = it >> 2, c = (it >> 1) & 1, j0 = (it & 1) * 4;
        const float* gp = gbase + sub * 16 + (c * 32 + quad * 8 + j0) * HW;
        const float x0 = gp[0 * HW], x1 = gp[1 * HW], x2 = gp[2 * HW], x3 = gp[3 * HW];

        short8 hv;
        hv[0] = (short)f2bf(v0.x); hv[1] = (short)f2bf(v0.y);
        hv[2] = (short)f2bf(v0.z); hv[3] = (short)f2bf(v0.w);
        hv[4] = (short)f2bf(v1.x); hv[5] = (short)f2bf(v1.y);
        hv[6] = (short)f2bf(v1.z); hv[7] = (short)f2bf(v1.w);
        *(short8*)(wh + g * 8) = hv;
        float ws2 = v0.x * v0.x;
        ws2 = fmaf(v0.y, v0.y, ws2); ws2 = fmaf(v0.z, v0.z, ws2);
        ws2 = fmaf(v0.w, v0.w, ws2); ws2 = fmaf(v1.x, v1.x, ws2);
        ws2 = fmaf(v1.y, v1.y, ws2); ws2 = fmaf(v1.z, v1.z, ws2);
        ws2 = fmaf(v1.w, v1.w, ws2);
        atomicAdd(&wsqp[tt * 16 + cc], ws2);  // LDS atomic

        ah[sub][c][j0 + 0] = (short)f2bf(-2.0f * x0);
        ah[sub][c][j0 + 1] = (short)f2bf(-2.0f * x1);
        ah[sub][c][j0 + 2] = (short)f2bf(-2.0f * x2);
        ah[sub][c][j0 + 3] = (short)f2bf(-2.0f * x3);
        xsq = fmaf(x0, x0, xsq); xsq = fmaf(x1, x1, xsq);
        xsq = fmaf(x2, x2, xsq); xsq = fmaf(x3, x3, xsq);
    }
    __syncthreads();  // B2: wh + wsqp complete

    // ---- scan 32 tiles of 16 codes; key = (float_bits(d)<<9)|code ----
    unsigned runkey[2][4];
#pragma unroll
    for (int sub = 0; sub < 2; ++sub)
#pragma unroll
        for (int r = 0; r < 4; ++r) runkey[sub][r] = 0xFFFFFFFFu;

#pragma unroll 1
    for (int t = 0; t < 32; ++t) {
        const unsigned short* ph = wh + t * 1024 + quad * 128 + col * 8;
        const short8 b0 = *(const short8*)ph;
        const short8 b1 = *(const short8*)(ph + 512);
        const int code = t * 16 + col;
        const float seed = wsqp[code];
#pragma unroll
        for (int sub = 0; sub < 2; ++sub) {
            f32x4 acc = {seed, seed, seed, seed};
            acc = __builtin_amdgcn_mfma_f32_16x16x32_bf16(ah[sub][0], b0, acc, 0, 0, 0);
            acc = __builtin_amdgcn_mfma_f32_16x16x32_bf16(ah[sub][1], b1, acc, 0, 0, 0);
#pragma unroll
            for (int r = 0; r < 4; ++r) {
                const unsigned key = (__float_as_uint(acc[r]) << 9) | code;
                runkey[sub][r] = key < runkey[sub][r] ? key : runkey[sub][r];
            }
        }
    }

    // ---- cross-lane argmin over the 16 code-cols ----
#pragma unroll
    for (int s = 1; s < 16; s <<= 1)
#pragma unroll
        for (int sub = 0; sub < 2; ++sub)
#pragma unroll
            for (int r = 0; r < 4; ++r) {
                const unsigned o = __shfl_xor(runkey[sub][r], s, 64);
                runkey[sub][r] = o < runkey[sub][r] ? o : runkey[sub][r];
            }

    // d_best (exact from key) + publish indices
    float dsum = 0.f;
    if (col == 0) {
#pragma unroll
        for (int sub = 0; sub < 2; ++sub)
#pragma unroll
            for (int r = 0; r < 4; ++r) {
                const unsigned key = runkey[sub][r];
                idxbuf[wv * 32 + sub * 16 + quad * 4 + r] = (int)(key & 511u);
                dsum += __uint_as_float((key >> 9) | 0x3F800000u) - 1.25f;
            }
    }
    float contrib = xsq + dsum;
#pragma unroll
    for (int off = 32; off > 0; off >>= 1) contrib += __shfl_down(contrib, off, 64);
    if (lane == 0) sred[wv] = (double)contrib;
    __syncthreads();  // B3: idxbuf + sred visible

    if (tid < 256) atomicAdd(&hist[idxbuf[tid]], 1);  // LDS histogram

    // ---- epilogue: write w rows only (L2-hot); 4 lanes/token, 2 passes ----
#pragma unroll
    for (int p = 0; p < 2; ++p) {
        const int tl = p * 16 + (lane >> 2), q = lane & 3;
        const int n = ntok0 + wv * 32 + tl;
        const int bidx = idxbuf[wv * 32 + tl];
        const float4* wr = (const float4*)(w + bidx * 64 + q * 16);
        float4* op = (float4*)(out + n * 64 + q * 16);
#pragma unroll
        for (int i = 0; i < 4; ++i) op[i] = wr[i];
    }
    __syncthreads();  // B4: hist complete

    if (!amode) {
        pcounts[(blockIdx.x << 9) + tid] = (float)hist[tid];  // plain store
        if (tid == 0) {
            double s = sred[0];
#pragma unroll
            for (int i = 1; i < 8; ++i) s += sred[i];
            ssep[blockIdx.x] = s;
        }
    } else {  // fallback: ws too small for partials
        const int h = hist[tid];
        if (h) atomicAdd(&counts[tid], (float)h);
        if (tid == 0) {
            double s = sred[0];
#pragma unroll
            for (int i = 1; i < 8; ++i) s += sred[i];
            atomicAdd(sse_acc, s);
        }
    }
}

// parallel reduce: thread t owns 4 codes x 1 block-quarter; float4 coalesced
__global__ __launch_bounds__(512) void vq_final_p(const float* __restrict__ pcounts,
                                                  const double* __restrict__ ssep,
                                                  float* __restrict__ out) {
    __shared__ float part[4][512];   // 8 KB: quarter x code
    __shared__ double red[512];
    __shared__ double sred[512];
    const int t = threadIdx.x;
    const int q = t >> 7, c4 = (t & 127) << 2;

    const float4* base = (const float4*)pcounts + (q << 14) + (c4 >> 2);
    float4 s = {0.f, 0.f, 0.f, 0.f};
#pragma unroll 16
    for (int b = 0; b < 128; ++b) {        // rows q*128 .. q*128+128
        const float4 v = base[b << 7];     // stride 512 floats = 128 float4
        s.x += v.x; s.y += v.y; s.z += v.z; s.w += v.w;
    }
    *(float4*)&part[q][c4] = s;
    sred[t] = ssep[t];
    __syncthreads();

    const float cnt = part[0][t] + part[1][t] + part[2][t] + part[3][t];
    const double p = (double)cnt / (double)NTOK;
    red[t] = p * log(p + 1e-10);
    __syncthreads();
#pragma unroll
    for (int st = 256; st > 0; st >>= 1) {
        if (t < st) { red[t] += red[t + st]; sred[t] += sred[t + st]; }
        __syncthreads();
    }
    if (t == 0) {
        out[NELEM] = (float)((sred[0] / (double)NELEM) * 1.25);
        out[NELEM + 1] = (float)exp(-red[0]);
    }
}

__global__ __launch_bounds__(512) void vq_final_a(const float* __restrict__ counts,
                                                  const double* __restrict__ sse_acc,
                                                  float* __restrict__ out) {
    __shared__ double red[512];
    const int k = threadIdx.x;
    const double p = (double)counts[k] / (double)NTOK;
    red[k] = p * log(p + 1e-10);
    __syncthreads();
#pragma unroll
    for (int st = 256; st > 0; st >>= 1) {
        if (k < st) red[k] += red[k + st];
        __syncthreads();
    }
    if (k == 0) {
        out[NELEM] = (float)((*sse_acc / (double)NELEM) * 1.25);
        out[NELEM + 1] = (float)exp(-red[0]);
    }
}

extern "C" void kernel_launch(void* const* d_in, const int* in_sizes, int n_in,
                              void* d_out, int out_size, void* d_ws, size_t ws_size,
                              hipStream_t stream) {
    const float* in = (const float*)d_in[0];
    const float* w = (const float*)d_in[1];
    float* out = (float*)d_out;
    char* ws = (char*)d_ws;

    const size_t need = (size_t)512 * 512 * 4 + 512 * 8;  // 1 MB + 4 KB
    if (ws_size >= need) {
        float* pcounts = (float*)ws;
        double* ssep = (double*)(ws + (size_t)512 * 512 * 4);
        vq_main<<<512, 512, 0, stream>>>(in, w, out, pcounts, ssep,
                                         nullptr, nullptr, 0);
        vq_final_p<<<1, 512, 0, stream>>>(pcounts, ssep, out);
    } else {  // fallback: R6-style atomics
        float* counts = (float*)ws;
        double* sse_acc = (double*)(ws + 2048);
        hipMemsetAsync(ws, 0, 2056, stream);
        vq_main<<<512, 512, 0, stream>>>(in, w, out, nullptr, nullptr,
                                         counts, sse_acc, 1);
        vq_final_a<<<1, 512, 0, stream>>>(counts, sse_acc, out);
    }
}